// Round 9
// baseline (23.348 us; speedup 1.0000x reference)
//
#include <hip/hip_runtime.h>
#include <math.h>

#define N_MC 256
#define CB 512                 // threads per block (8 waves)
#define MPB 256                // m's per block
#define MAIN_BLOCKS 1024       // MPB * MAIN_BLOCKS == 262144 == M

constexpr float  WF        = 2.5f;
constexpr float  LOG2PI_F  = 1.8378770664093453f;   // log(2*pi)
constexpr float  L2E       = 1.4426950408889634f;   // log2(e)
constexpr float  LN2_F     = 0.6931471805599453f;
constexpr float  PI_F      = 3.14159265358979323846f;
constexpr float  GAMMA_1_5 = 0.8862269254527580f;   // Gamma(1.5)
constexpr float  ERFW_C    = 0.98758066934f;        // erf(2.5/sqrt(2))
constexpr float  GMIN_C    = 0.04393693362f;        // exp(-2.5^2/2)

typedef float v2f __attribute__((ext_vector_type(2)));

__device__ __forceinline__ float fexp2(float x) { return __builtin_amdgcn_exp2f(x); }
__device__ __forceinline__ float flog2(float x) { return __builtin_amdgcn_logf(x); }
__device__ __forceinline__ v2f  splat(float v) { return (v2f){v, v}; }

// ---------------- setup: per-n constants + uniform scalar block ----------
// scal[] layout:
// 0 inv2A  1 four_sn2  2 CONST0  3 beta  4 inv_sn2  5 nC2  6 lw0  7 lw1
// 8 lw2    9 base12   10 Qc    11 K    12 c2n      13 I1  14 I2  15 A
__global__ void setup_kernel(const float* __restrict__ k_u,
                             const float* p_sb, const float* p_sn,
                             const float* p_I1, const float* p_I2,
                             const float* w1, const float* w2, const float* w12,
                             float* __restrict__ nPp, float* __restrict__ nT,
                             float* __restrict__ nB, float* __restrict__ scal) {
    int n = threadIdx.x;
    float sb = *p_sb, sn = *p_sn, I1 = *p_I1, I2 = *p_I2;
    float sn2 = sn * sn, inv_sn2 = 1.0f / sn2, c2n = 0.5f * inv_sn2;
    float dI = I2 - I1;
    float I_diff = dI * ERFW_C;
    float I_min  = I1 + 0.5f * dI * (1.0f - ERFW_C);
    float A = dI * rsqrtf(2.0f * PI_F * sb * sb);

    // per-n constants (log2 domain): s = Pp + T*x + B*y + nC2*x^2
    float tx = k_u[n] * I_diff + I_min;
    float u  = 2.0f * (tx - I1) / dI - 1.0f;
    float ei = erfinvf(u);
    float e2 = ei * ei;
    float lptx = -logf(2.0f * WF * dI) + 0.5f * LOG2PI_F + e2;
    float G = A * expf(-e2);
    float b = 2.0f * G / sn2;       // z = b*y
    float P = lptx - 0.5f * logf(G) - 0.5f * logf(b) - G * G / sn2
            - 2.0f * logf(sn) + 0.5f * logf(2.0f / PI_F);
    nPp[n] = (P - c2n * tx * tx) * L2E;
    nT[n]  = (tx * inv_sn2) * L2E;
    nB[n]  = b * L2E;

    if (n == 0) {
        float r0 = *w1, r1 = *w2, r2 = *w12;
        float rm = fmaxf(r0, fmaxf(r1, r2));
        float lse_r = rm + logf(expf(r0 - rm) + expf(r1 - rm) + expf(r2 - rm));
        scal[0]  = 0.5f / A;
        scal[1]  = 4.0f * sn2;
        scal[2]  = -logf(2.0f * WF * dI) - logf(A) - logf(sn) + 0.5f * LN2_F;
        scal[3]  = 2.0f * A * inv_sn2;
        scal[4]  = inv_sn2;
        scal[5]  = -c2n * L2E;
        scal[6]  = r0 - lse_r;
        scal[7]  = r1 - lse_r;
        scal[8]  = r2 - lse_r;
        scal[9]  = logf(I_diff) - 8.0f * LN2_F;
        scal[10] = -logf(sn) - 0.5f * LOG2PI_F;
        scal[11] = LN2_F - logf(GAMMA_1_5) - 4.0f * logf(sn) - 0.5f * LOG2PI_F;
        scal[12] = c2n;
        scal[13] = I1;
        scal[14] = I2;
        scal[15] = A;
    }
}

// ---------------- main: 8-wave n-split, 4 m/thread, pk fp32 ----------
#define PAIRV(Pj, Tj, Bj)                                                     \
    {                                                                         \
        v2f s01 = __builtin_elementwise_fma(splat(Tj), x01,                   \
                   __builtin_elementwise_fma(splat(Bj), y01, d01))            \
                  + splat(Pj);                                                \
        v2f s23 = __builtin_elementwise_fma(splat(Tj), x23,                   \
                   __builtin_elementwise_fma(splat(Bj), y23, d23))            \
                  + splat(Pj);                                                \
        v2f e01, e23;                                                         \
        e01.x = fexp2(s01.x); e01.y = fexp2(s01.y);                           \
        e23.x = fexp2(s23.x); e23.y = fexp2(s23.y);                           \
        a01 += e01; a23 += e23;                                               \
    }

__global__ __launch_bounds__(CB, 8) void main_kernel(
        const float* __restrict__ x_g, const float* __restrict__ y_g,
        const float* __restrict__ nPp, const float* __restrict__ nT,
        const float* __restrict__ nB, const float* __restrict__ scal,
        double* __restrict__ partials) {

    __shared__ float  sPp[N_MC], sT[N_MC], sB[N_MC];
    __shared__ float4 srec[MPB];
    __shared__ float  part[8][MPB];
    __shared__ double sred[4];

    int tid  = threadIdx.x;
    int wv   = tid >> 6;
    int lane = tid & 63;
    int mb   = blockIdx.x * MPB;

    // uniform scalar block (SGPR loads)
    float inv2A    = scal[0];
    float four_sn2 = scal[1];
    float CONST0   = scal[2];
    float beta     = scal[3];
    float inv_sn2  = scal[4];
    float nC2      = scal[5];

    if (tid < N_MC) {
        sPp[tid] = nPp[tid];
        sT[tid]  = nT[tid];
        sB[tid]  = nB[tid];
    } else {
        // per-m record {x, y, D2, Cl2} for mi = tid-256
        int mi = tid - N_MC;
        int m  = mb + mi;
        float xv = x_g[m], yv = y_g[m];
        // analytic upper bound C on max_n (P + b*y): unimodal in g
        float disc = fmaf(yv, yv, -four_sn2);
        float root = sqrtf(fmaxf(disc, 0.0f));
        float gs = (yv + root) * inv2A;
        gs = fminf(fmaxf(gs, GMIN_C), 1.0f);
        float Ag = gs * scal[15];
        float Cnn = CONST0 - 2.0f * flog2(gs) * LN2_F - Ag * Ag * inv_sn2
                  + beta * gs * yv;
        float Cl2 = fmaf(Cnn, L2E, 2.0f);         // +2 bits safety margin
        float D2  = fmaf(nC2 * xv, xv, -Cl2);     // nC2*x^2 - C
        srec[mi] = make_float4(xv, yv, D2, Cl2);
    }
    __syncthreads();

    // ---- each thread: 4 m's from LDS, packed as 2 x float2 ----
    float4 r0v = srec[lane];
    float4 r1v = srec[64 + lane];
    float4 r2v = srec[128 + lane];
    float4 r3v = srec[192 + lane];
    v2f x01 = {r0v.x, r1v.x}, y01 = {r0v.y, r1v.y}, d01 = {r0v.z, r1v.z};
    v2f x23 = {r2v.x, r3v.x}, y23 = {r2v.y, r3v.y}, d23 = {r2v.z, r3v.z};

    const float4* P4 = (const float4*)sPp;
    const float4* T4 = (const float4*)sT;
    const float4* B4 = (const float4*)sB;
    int g0 = wv * 8;

    v2f a01 = {0.0f, 0.0f}, a23 = {0.0f, 0.0f};
#pragma unroll 2
    for (int g = 0; g < 8; ++g) {
        float4 P = P4[g0 + g];
        float4 T = T4[g0 + g];
        float4 B = B4[g0 + g];
        PAIRV(P.x, T.x, B.x)
        PAIRV(P.y, T.y, B.y)
        PAIRV(P.z, T.z, B.z)
        PAIRV(P.w, T.w, B.w)
    }

    part[wv][lane]       = a01.x;
    part[wv][lane + 64]  = a01.y;
    part[wv][lane + 128] = a23.x;
    part[wv][lane + 192] = a23.y;
    __syncthreads();

    // ---- epilogue: mixture LSE per m (threads 0..255), wave butterfly ----
    if (tid < MPB) {
        float lw0    = scal[6],  lw1 = scal[7], lw2 = scal[8];
        float base12 = scal[9],  Qc  = scal[10], K = scal[11];
        float c2n    = scal[12], I1  = scal[13], I2 = scal[14];
        int mi = tid;
        float sm = 0.0f;
#pragma unroll
        for (int w = 0; w < 8; ++w) sm += part[w][mi];
        float4 rr = srec[mi];
        float xv = rr.x, yv = rr.y, Cl2 = rr.w;
        float ly  = flog2(yv) * LN2_F;
        float y2s = yv * yv * inv_sn2;
        float lp12 = base12 + ly - y2s + Qc + LN2_F * (Cl2 + flog2(sm));
        float e1 = xv - I1, e2v = xv - I2;
        float base_i = K + 2.0f * ly - y2s;
        float lp1 = base_i - c2n * e1 * e1;
        float lp2 = base_i - c2n * e2v * e2v;
        float b0 = lw0 + lp1, b1 = lw1 + lp2, b2 = lw2 + lp12;
        float mm = fmaxf(b0, fmaxf(b1, b2));
        float lp = mm + LN2_F * flog2(fexp2((b0 - mm) * L2E)
                  + fexp2((b1 - mm) * L2E) + fexp2((b2 - mm) * L2E));
        double lpd = (double)lp;
#pragma unroll
        for (int o = 32; o > 0; o >>= 1) lpd += __shfl_xor(lpd, o, 64);
        if (lane == 0) sred[wv] = lpd;
    }
    __syncthreads();
    if (tid == 0) partials[blockIdx.x] = (sred[0] + sred[1]) + (sred[2] + sred[3]);
}

// ---------------- final reduction ----------------
__global__ void reduce_kernel(const double* __restrict__ partials, float* __restrict__ out) {
    __shared__ double red[256];
    double a = 0.0;
    for (int i = threadIdx.x; i < MAIN_BLOCKS; i += 256) a += partials[i];
    red[threadIdx.x] = a;
    __syncthreads();
    for (int s = 128; s > 0; s >>= 1) {
        if (threadIdx.x < s) red[threadIdx.x] += red[threadIdx.x + s];
        __syncthreads();
    }
    if (threadIdx.x == 0) out[0] = (float)(-red[0]);
}

extern "C" void kernel_launch(void* const* d_in, const int* in_sizes, int n_in,
                              void* d_out, int out_size, void* d_ws, size_t ws_size,
                              hipStream_t stream) {
    const float* x   = (const float*)d_in[0];
    const float* y   = (const float*)d_in[1];
    const float* k_u = (const float*)d_in[2];
    const float* sb  = (const float*)d_in[3];
    const float* sn  = (const float*)d_in[4];
    const float* I1  = (const float*)d_in[5];
    const float* I2  = (const float*)d_in[6];
    const float* w1  = (const float*)d_in[7];
    const float* w2  = (const float*)d_in[8];
    const float* w12 = (const float*)d_in[9];

    char* ws = (char*)d_ws;
    float*  nPp      = (float*)ws;                   // 256 floats
    float*  nT       = nPp + N_MC;                   // 256
    float*  nB       = nT + N_MC;                    // 256
    float*  scal     = nB + N_MC;                    // 16
    double* partials = (double*)(ws + 3264);         // 3*1024+64 = 3136... padded

    // (3*256+16)*4 = 3136 bytes; partials at 3264 (8-aligned, padded)
    setup_kernel<<<1, N_MC, 0, stream>>>(k_u, sb, sn, I1, I2, w1, w2, w12,
                                         nPp, nT, nB, scal);
    main_kernel<<<MAIN_BLOCKS, CB, 0, stream>>>(x, y, nPp, nT, nB, scal, partials);
    reduce_kernel<<<1, 256, 0, stream>>>(partials, (float*)d_out);
}